// Round 11
// baseline (154.783 us; speedup 1.0000x reference)
//
#include <hip/hip_runtime.h>
#include <stdint.h>

typedef unsigned long long u64;
typedef unsigned int u32;

#define N_ANCH     36864
#define PRE_NMS_N  6000
#define POST_NMS_N 300
#define NBINS_F    8192     // fallback full bin count
#define PF_BIN     1536     // pre-filter: bins < 1536 (score >= 0.8125); E[count]=6912, 11.7 sigma above 6000
#define BCAP       24       // bucket capacity: lambda=4.5, P(any bin>24) ~ 1e-7 -> exact fallback
#define GKH_CAP    8192
#define NWORDS     94       // ceil(6000/64)
#define S_WORDS    8        // staged words (candidates 0..511)
#define S_ROWS     512
#define GRID_A     144      // 144 x 256 == N_ANCH
#define BLK_A      256
#define GRID_B     256      // rows {b, b+256} per block

// ---- workspace layout (bytes) ----
#define OFF_BBOX   0            // float4 bbox[36864]       589824
#define OFF_KEYS   589824       // u64 keys[36864]          294912 (fallback only)
#define OFF_SBOX   884736       // float4 sboxes[6000]       96000
#define OFF_IREM   980736       // u64 irem[94]                752
#define OFF_CTR    981488       // ctrA u64, ctrB u64
#define OFF_BCTR   981504       // u32 bctr[1536]             6144  (memset 0 per call)
#define OFF_GBUCK  987648       // u64 gbuck[1536*24]       294912
#define OFF_MCOL   1282560      // u64 Mcol[8*512]           32768  (column/word-major)
#define WS_FULL    (OFF_MCOL + (size_t)S_WORDS * S_ROWS * 8)

// Value-uniform monotone bin: higher score -> lower bin.
__device__ __forceinline__ u32 score_bin(float s) {
    float v = fminf(fmaxf(s, 0.0f), 1.0f);
    u32 q = (u32)(v * 8192.0f);
    if (q > 8191u) q = 8191u;
    return 8191u - q;
}

// key = bin(16) | sortable_score(32) | idx(16); ascending u64 ==
// (score desc, idx asc) exactly.
__device__ __forceinline__ u64 make_key(float s, u32 bin, u32 idx) {
    u32 u = __float_as_uint(s);
    u32 sortable = u ^ ((u >> 31) ? 0xFFFFFFFFu : 0x80000000u);
    u32 hi = ~sortable;
    return ((u64)bin << 48) | ((u64)hi << 16) | (u64)idx;
}

__device__ __forceinline__ u64 readlane_u64(u64 v, int l) {
    u32 lo = __builtin_amdgcn_readlane((u32)(v & 0xFFFFFFFFull), l);
    u32 hi = __builtin_amdgcn_readlane((u32)(v >> 32), l);
    return ((u64)hi << 32) | (u64)lo;
}

__device__ __forceinline__ int nth_set_bit(u64 m, int n) {
    int pos = 0;
    u32 c = __popc((u32)m);
    if ((u32)n >= c) { n -= c; pos = 32; m >>= 32; }
    u32 x = (u32)m;
    c = __popc(x & 0xFFFFu);
    if ((u32)n >= c) { n -= c; pos += 16; x >>= 16; }
    c = __popc(x & 0xFFu);
    if ((u32)n >= c) { n -= c; pos += 8; x >>= 8; }
    c = __popc(x & 0xFu);
    if ((u32)n >= c) { n -= c; pos += 4; x >>= 4; }
    c = __popc(x & 0x3u);
    if ((u32)n >= c) { n -= c; pos += 2; x >>= 2; }
    c = x & 1u;
    if ((u32)n >= c) { pos += 1; }
    return pos;
}

// EXACT reference IoU decision (identical expression tree to all prior rounds)
__device__ __forceinline__ bool iou_gt(float4 a, float4 b) {
    float aa = (a.z - a.x) * (a.w - a.y);
    float ab = (b.z - b.x) * (b.w - b.y);
    float xx1 = fmaxf(a.x, b.x), yy1 = fmaxf(a.y, b.y);
    float xx2 = fminf(a.z, b.z), yy2 = fminf(a.w, b.w);
    float inter = fmaxf(xx2 - xx1, 0.0f) * fmaxf(yy2 - yy1, 0.0f);
    float iou = inter / (aa + ab - inter + 1e-9f);
    return iou > 0.7f;
}

// ===== K_FRONT: decode + bucket-direct scatter (all blocks);
//       last-arriving block: scan counts + in-bucket rank -> sboxes + irem =====
__global__ __launch_bounds__(BLK_A) void k_front(const float4* __restrict__ anchors,
                                                 const float* __restrict__ cls,
                                                 const float4* __restrict__ reg,
                                                 const int* __restrict__ img_w,
                                                 const int* __restrict__ img_h,
                                                 float4* __restrict__ bbox,
                                                 u64* __restrict__ keys,
                                                 u32* __restrict__ bctr,
                                                 u64* __restrict__ gbuck,
                                                 float4* __restrict__ sboxes,
                                                 u64* __restrict__ irem,
                                                 u64* __restrict__ ctrA) {
    __shared__ u32 offsL[PF_BIN + 1];      // happy: bucket offsets   (6148 B)
    __shared__ u32 histF[NBINS_F];         // fallback hist->offs    (32 KiB)
    __shared__ u32 cntF[NBINS_F];          // fallback               (32 KiB)
    __shared__ u64 gkB[GKH_CAP];           // fallback               (64 KiB)
    __shared__ u64 iremL[NWORDS];
    __shared__ u32 wsum[4];
    __shared__ u32 mB, mM, lastflag, ovfF, offs_top;

    int tid = threadIdx.x, lane = tid & 63, wave = tid >> 6;
    int gi = blockIdx.x * BLK_A + tid;     // exact: 144*256 == N_ANCH

    // ---- decode + clip + valid + key (EXACT reference arithmetic) ----
    {
        float4 a = anchors[gi];
        float4 r = reg[gi];
        float w  = a.z - a.x, h = a.w - a.y;
        float cx = a.x + 0.5f * w, cy = a.y + 0.5f * h;
        float pcx = r.x * w + cx, pcy = r.y * h + cy;
        float pw = expf(r.z) * w,  ph = expf(r.w) * h;
        float b0 = pcx - 0.5f * pw, b1 = pcy - 0.5f * ph;
        float b2 = pcx + 0.5f * pw, b3 = pcy + 0.5f * ph;

        float fh = (float)img_h[0], fw = (float)img_w[0];
        b0 = fminf(fmaxf(b0, 0.0f), fh);
        b2 = fminf(fmaxf(b2, 0.0f), fh);
        b1 = fminf(fmaxf(b1, 0.0f), fw);
        b3 = fminf(fmaxf(b3, 0.0f), fw);

        bool valid = (b2 - b0 >= 16.0f) && (b3 - b1 >= 16.0f);
        float score = valid ? cls[gi] : -1e9f;

        bbox[gi] = make_float4(b0, b1, b2, b3);
        u32 bin = score_bin(score);
        u64 key = make_key(score, bin, (u32)gi);
        keys[gi] = key;

        // bucket-direct scatter (bin<1536 => score>=0.8125 => valid)
        if (bin < (u32)PF_BIN) {
            u32 slot = atomicAdd(&bctr[bin], 1u);
            if (slot < (u32)BCAP) gbuck[bin * BCAP + slot] = key;
        }
    }

    // ---- arrival (monotone modulo counter: poison-proof, no reset) ----
    __syncthreads();
    if (tid == 0) {
        __threadfence();
        u64 old = atomicAdd(ctrA, 1ull);
        lastflag = ((old % (u64)GRID_A) == (u64)(GRID_A - 1)) ? 1u : 0u;
        ovfF = 0u;
    }
    __syncthreads();
    if (!lastflag) return;
    __threadfence();   // acquire: see all blocks' bbox/keys/bctr/gbuck

    if (tid < NWORDS) iremL[tid] = ~0ull;

    // ---- read bucket counts (6/thread), clamp, detect overflow ----
    u32 cl[6]; u32 s = 0; bool ovf = false;
    int base = tid * 6;
#pragma unroll
    for (int t = 0; t < 6; ++t) {
        u32 c = bctr[base + t];
        ovf = ovf || (c > (u32)BCAP);
        cl[t] = c > (u32)BCAP ? (u32)BCAP : c;
        s += cl[t];
    }
    if (ovf) atomicOr(&ovfF, 1u);

    // ---- 2-barrier scan (wave shfl + 4-partial combine) ----
    u32 incv = s;
#pragma unroll
    for (int off = 1; off < 64; off <<= 1) {
        u32 v = (u32)__shfl_up((int)incv, off, 64);
        if (lane >= off) incv += v;
    }
    if (lane == 63) wsum[wave] = incv;
    __syncthreads();
    if (tid == 0) {
        u32 run = 0;
#pragma unroll
        for (int k2 = 0; k2 < 4; ++k2) { u32 t2 = wsum[k2]; wsum[k2] = run; run += t2; }
    }
    __syncthreads();
    u32 incl = wsum[wave] + incv;
    u32 excl = incl - s;
    u32 run = excl;
#pragma unroll
    for (int t = 0; t < 6; ++t) { offsL[base + t] = run; run += cl[t]; }
    if (tid == BLK_A - 1) offsL[PF_BIN] = incl;
    __syncthreads();

    u32 count = offsL[PF_BIN];
    bool happy = (count >= (u32)PRE_NMS_N) && (ovfF == 0u);

    if (happy) {
        // ---- per-bin rank directly from gbuck (L2-hot) ----
#pragma unroll
        for (int t = 0; t < 6; ++t) {
            int b = base + t;
            u32 o = offsL[b], c = cl[t];
            if (o < (u32)PRE_NMS_N && c) {
                const u64* bp = gbuck + b * BCAP;
                for (u32 i = 0; i < c; ++i) {
                    u64 ki = bp[i];
                    u32 r = o;
                    for (u32 j = 0; j < c; ++j) r += (bp[j] < ki) ? 1u : 0u;
                    if (r < (u32)PRE_NMS_N) {
                        u32 idx = (u32)(ki & 0xFFFFu);
                        sboxes[r] = bbox[idx];
                        atomicAnd(&iremL[r >> 6], ~(1ull << (r & 63)));
                    }
                }
            }
        }
    } else {
        // ---- exact fallback: full 8192-bin path over all keys ----
        for (int b = tid; b < NBINS_F; b += BLK_A) { histF[b] = 0u; cntF[b] = 0u; }
        __syncthreads();
        for (int i = tid; i < N_ANCH; i += BLK_A)
            atomicAdd(&histF[(u32)(keys[i] >> 48)], 1u);
        __syncthreads();
        u32 loc[32]; u32 sF = 0;
        int base32 = tid * 32;
#pragma unroll
        for (int t = 0; t < 32; ++t) { loc[t] = histF[base32 + t]; sF += loc[t]; }
        u32 iv = sF;
#pragma unroll
        for (int off = 1; off < 64; off <<= 1) {
            u32 v = (u32)__shfl_up((int)iv, off, 64);
            if (lane >= off) iv += v;
        }
        if (lane == 63) wsum[wave] = iv;
        __syncthreads();
        if (tid == 0) {
            u32 rn = 0;
#pragma unroll
            for (int k2 = 0; k2 < 4; ++k2) { u32 t2 = wsum[k2]; wsum[k2] = rn; rn += t2; }
        }
        __syncthreads();
        u32 inclF = wsum[wave] + iv;
        u32 exclF = inclF - sF;
        u32 rn = exclF;
#pragma unroll
        for (int t = 0; t < 32; ++t) { histF[base32 + t] = rn; rn += loc[t]; }
        if (tid == BLK_A - 1) offs_top = inclF;
        if (exclF < (u32)PRE_NMS_N && inclF >= (u32)PRE_NMS_N) {
            u32 c = exclF;
#pragma unroll
            for (int t = 0; t < 32; ++t) {
                if (c + loc[t] >= (u32)PRE_NMS_N) { mB = (u32)(base32 + t); mM = c + loc[t]; break; }
                c += loc[t];
            }
        }
        __syncthreads();
        u32 B = mB;
        for (int i = tid; i < N_ANCH; i += BLK_A) {
            u64 k = keys[i];
            u32 bn = (u32)(k >> 48);
            if (bn <= B) {
                u32 p = histF[bn] + atomicAdd(&cntF[bn], 1u);
                if (p < (u32)GKH_CAP) gkB[p] = k;
            }
        }
        __syncthreads();
        u32 Mtot = mM > (u32)GKH_CAP ? (u32)GKH_CAP : mM;
        for (int i = tid; i < (int)Mtot; i += BLK_A) {
            u64 k = gkB[i];
            u32 bn = (u32)(k >> 48);
            u32 st = histF[bn];
            u32 en = (bn + 1 < (u32)NBINS_F) ? histF[bn + 1] : offs_top;
            if (en > (u32)GKH_CAP) en = (u32)GKH_CAP;
            u32 rr = st;
            for (u32 t = st; t < en; ++t) rr += (gkB[t] < k) ? 1u : 0u;
            if (rr < (u32)PRE_NMS_N) {
                u32 idx = (u32)(k & 0xFFFFu);
                float4 b = bbox[idx];
                sboxes[rr] = b;
                bool valid = (b.z - b.x >= 16.0f) && (b.w - b.y >= 16.0f);
                if (valid) atomicAnd(&iremL[rr >> 6], ~(1ull << (rr & 63)));
            }
        }
    }
    __syncthreads();
    if (tid < NWORDS) irem[tid] = iremL[tid];
}

// ===== K_BACK: eager IoU rows<512 x words<8 -> column-major Mcol (all blocks);
//       last block: coalesced stage + wholesale-word reduce =====
__global__ __launch_bounds__(64) void k_back(const float4* __restrict__ sboxes,
                                             const u64* __restrict__ irem,
                                             u64* __restrict__ Mcol,
                                             u64* __restrict__ ctrB,
                                             float* __restrict__ out) {
    __shared__ float4 sbL[PRE_NMS_N];      // fallback staging only (96000 B)
    __shared__ u64 S[S_WORDS * S_ROWS];    // 32768 B == Mcol layout
    __shared__ u64 kmaskLDS[NWORDS];
    __shared__ u32 kbaseLDS[NWORDS];
    __shared__ u32 lastflag;
    int lane = threadIdx.x;

    // ---- eager: rows {bid, bid+256}, words row>>6 .. 7; write COLUMN-major ----
#pragma unroll
    for (int t = 0; t < 2; ++t) {
        int i = blockIdx.x + (t << 8);     // < 512
        float4 bi = sboxes[i];
        for (int w = i >> 6; w < S_WORDS; ++w) {
            int j = (w << 6) + lane;       // < 512
            bool sup = (j > i) && iou_gt(bi, sboxes[j]);
            u64 m = __ballot(sup);
            if (lane == 0) Mcol[w * S_ROWS + i] = m;
        }
    }

    // ---- arrival (monotone modulo counter) ----
    __syncthreads();
    if (lane == 0) {
        __threadfence();
        u64 old = atomicAdd(ctrB, 1ull);
        lastflag = ((old % (u64)GRID_B) == (u64)(GRID_B - 1)) ? 1u : 0u;
    }
    __syncthreads();
    if (!lastflag) return;
    __threadfence();   // acquire

    // coalesced stage: S layout == Mcol layout
    for (int idx = lane; idx < S_WORDS * S_ROWS; idx += 64)
        S[idx] = Mcol[idx];
    __syncthreads();
    u64 lanebit = 1ull << lane;
    u64 riem0 = irem[lane];
    u64 riem1 = (lane < NWORDS - 64) ? irem[64 + lane] : ~0ull;

    int kc = 0, wend = 0;
    bool sbStaged = false;
    for (int w = 0; w < NWORDS && kc < POST_NMS_N; ++w) {
        int q0 = w << 6;
        u64 avail, myrow;

        if (w < S_WORDS) {
            u64 add = 0;
            for (int wp = 0; wp < w; ++wp) {
                u64 km = kmaskLDS[wp];
                if (km & lanebit) add |= S[w * S_ROWS + (wp << 6) + lane];
            }
            if (w) {
#pragma unroll
                for (int off = 32; off >= 1; off >>= 1) add |= __shfl_xor(add, off, 64);
            }
            u64 iw = readlane_u64(riem0, w);
            avail = ~(iw | add);
            u64 diag = S[w * S_ROWS + q0 + lane];
            bool ina = (avail >> lane) & 1ull;
            myrow = ina ? (diag & avail) : 0ull;
        } else {
            // exact on-the-fly fallback (only if >212 of first 512 suppressed)
            if (!sbStaged) {
                for (int r2 = lane; r2 < PRE_NMS_N; r2 += 64) sbL[r2] = sboxes[r2];
                sbStaged = true;
                __syncthreads();
            }
            int j = q0 + lane; if (j >= PRE_NMS_N) j = PRE_NMS_N - 1;
            float4 bj = sbL[j];
            bool sup = false;
            for (int wp = 0; wp < w; ++wp) {
                u64 km = kmaskLDS[wp];
                while (km) {
                    int b = __ffsll((unsigned long long)km) - 1; km &= km - 1;
                    sup = sup || iou_gt(sbL[(wp << 6) + b], bj);
                }
            }
            u64 iw = (w < 64) ? readlane_u64(riem0, w) : readlane_u64(riem1, w - 64);
            avail = ~(iw | __ballot(sup));
            int irow = q0 + lane;
            bool rowok = (irow < PRE_NMS_N) && ((avail >> lane) & 1ull);
            float4 bi2 = sbL[rowok ? irow : 0];
            u64 my = 0;
            for (int m2 = lane + 1; m2 < 64; ++m2) {
                int jj = q0 + m2;
                if (jj >= PRE_NMS_N) break;
                if (iou_gt(bi2, sbL[jj])) my |= (1ull << m2);
            }
            myrow = rowok ? (my & avail) : 0ull;
        }

        u64 src = __ballot(myrow != 0ull);
        u64 tor = myrow;
#pragma unroll
        for (int off = 32; off >= 1; off >>= 1) tor |= __shfl_xor(tor, off, 64);
        u64 active = (src | tor) & avail;

        u64 rm = 0;
        while (active) {
            int b = __ffsll((unsigned long long)active) - 1;
            active &= active - 1;
            if (!((rm >> b) & 1ull)) rm |= readlane_u64(myrow, b);
        }
        u64 keptw = avail & ~rm;

        if (lane == 0) { kmaskLDS[w] = keptw; kbaseLDS[w] = (u32)kc; }
        kc += __popcll(keptw);
        wend = w + 1;
    }

    int nout = kc < POST_NMS_N ? kc : POST_NMS_N;
    for (int r2 = lane; r2 < POST_NMS_N; r2 += 64) {
        float4 v = make_float4(0.0f, 0.0f, 0.0f, 0.0f);
        if (r2 < nout) {
            int w = 0;
            while (w + 1 < wend && (int)kbaseLDS[w + 1] <= r2) ++w;
            int n = r2 - (int)kbaseLDS[w];
            int idx = (w << 6) + nth_set_bit(kmaskLDS[w], n);
            v = sboxes[idx];
        }
        ((float4*)out)[r2] = v;
    }
}

extern "C" void kernel_launch(void* const* d_in, const int* in_sizes, int n_in,
                              void* d_out, int out_size, void* d_ws, size_t ws_size,
                              hipStream_t stream) {
    const float4* anchors = (const float4*)d_in[0];
    const float*  cls     = (const float*)d_in[1];
    const float4* reg     = (const float4*)d_in[2];
    const int*    img_w   = (const int*)d_in[3];
    const int*    img_h   = (const int*)d_in[4];

    char* ws = (char*)d_ws;
    float4* bbox   = (float4*)(ws + OFF_BBOX);
    u64*    keys   = (u64*)   (ws + OFF_KEYS);
    float4* sboxes = (float4*)(ws + OFF_SBOX);
    u64*    irem   = (u64*)   (ws + OFF_IREM);
    u64*    ctrA   = (u64*)   (ws + OFF_CTR);
    u64*    ctrB   = (u64*)   (ws + OFF_CTR + 8);
    u32*    bctr   = (u32*)   (ws + OFF_BCTR);
    u64*    gbuck  = (u64*)   (ws + OFF_GBUCK);
    u64*    Mcol   = (u64*)   (ws + OFF_MCOL);

    hipMemsetAsync(bctr, 0, PF_BIN * sizeof(u32), stream);  // bucket counters

    k_front<<<dim3(GRID_A), dim3(BLK_A), 0, stream>>>(
        anchors, cls, reg, img_w, img_h, bbox, keys, bctr, gbuck, sboxes, irem, ctrA);

    k_back<<<dim3(GRID_B), dim3(64), 0, stream>>>(
        sboxes, irem, Mcol, ctrB, (float*)d_out);
}